// Round 9
// baseline (200.864 us; speedup 1.0000x reference)
//
#include <hip/hip_runtime.h>
#include <hip/hip_bf16.h>
#include <hip/hip_fp16.h>

typedef __attribute__((ext_vector_type(8))) _Float16 half8;  // 8 fp16 = 16x16x32 A/B frag
typedef __attribute__((ext_vector_type(4))) float f32x4;     // 16x16 C/D frag

#define BLOCK 256      // 4 waves
#define GTILE 16       // edges per wave-tile
#define NBKT  32       // dst buckets (0.8 MB dst-range each), bucket%8 -> XCD slot

// W region: logical [row][boff], 256-B rows, XOR ((row&15)<<4) (verified r4-r8).
__device__ __forceinline__ int swz16(int row, int boff) {
    return (row << 8) + (boff ^ ((row & 15) << 4));
}
// Z region: logical [halfrow][boff], 128-B rows, XOR ((row&7)<<4) (verified r4-r8).
__device__ __forceinline__ int swzH(int row, int boff) {
    return (row << 7) + (boff ^ ((row & 7) << 4));
}

__device__ __forceinline__ int probe_i64(const int* eli) {
    int any = 0;
    #pragma unroll
    for (int i = 0; i < 32; ++i) any |= eli[2 * i + 1];
    return (any == 0) ? 1 : 0;   // int64 little-endian: odd dwords (hi halves) all 0
}

// ---------------- pass 1: f32 -> fp16 tables + dst-bucket histogram ----------------
__global__ __launch_bounds__(256) void cvt_hist_kernel(
    const float* __restrict__ a, const float* __restrict__ b,
    _Float16* __restrict__ oa, _Float16* __restrict__ ob, int n,  // n = N*128
    const int* __restrict__ eli, int E, float scale, unsigned int* __restrict__ cnt)
{
    __shared__ unsigned int h[NBKT];
    __shared__ int s_i64;
    if (threadIdx.x < NBKT) h[threadIdx.x] = 0;
    if (threadIdx.x == 0) s_i64 = probe_i64(eli);
    __syncthreads();

    const int i = blockIdx.x * blockDim.x + threadIdx.x;
    const int stride = gridDim.x * blockDim.x;
    const float4* a4 = (const float4*)a;
    const float4* b4 = (const float4*)b;
    const int n8 = n >> 3;
    for (int j = i; j < n8; j += stride) {
        float4 x0 = a4[2 * j], x1 = a4[2 * j + 1];
        float4 y0 = b4[2 * j], y1 = b4[2 * j + 1];
        union { _Float16 hh[8]; uint4 u; } pa, pb;
        pa.hh[0]=(_Float16)x0.x; pa.hh[1]=(_Float16)x0.y;
        pa.hh[2]=(_Float16)x0.z; pa.hh[3]=(_Float16)x0.w;
        pa.hh[4]=(_Float16)x1.x; pa.hh[5]=(_Float16)x1.y;
        pa.hh[6]=(_Float16)x1.z; pa.hh[7]=(_Float16)x1.w;
        pb.hh[0]=(_Float16)y0.x; pb.hh[1]=(_Float16)y0.y;
        pb.hh[2]=(_Float16)y0.z; pb.hh[3]=(_Float16)y0.w;
        pb.hh[4]=(_Float16)y1.x; pb.hh[5]=(_Float16)y1.y;
        pb.hh[6]=(_Float16)y1.z; pb.hh[7]=(_Float16)y1.w;
        ((uint4*)oa)[j] = pa.u;
        ((uint4*)ob)[j] = pb.u;
    }
    for (int j = (n8 << 3) + i; j < n; j += stride) {
        oa[j] = (_Float16)a[j];
        ob[j] = (_Float16)b[j];
    }
    // histogram of dst bucket
    const int i64f = s_i64;
    for (int e = i; e < E; e += stride) {
        int c = i64f ? eli[2 * ((size_t)E + e)] : eli[(size_t)E + e];
        int bkt = (int)((float)c * scale);
        if (bkt > NBKT - 1) bkt = NBKT - 1;
        atomicAdd(&h[bkt], 1u);
    }
    __syncthreads();
    if (threadIdx.x < NBKT && h[threadIdx.x])
        atomicAdd(&cnt[threadIdx.x], h[threadIdx.x]);
}

// ---------------- pass 2: exclusive scan ----------------
__global__ void scan_kernel(const unsigned int* __restrict__ cnt,
                            unsigned int* __restrict__ segStart,
                            unsigned int* __restrict__ cursor)
{
    if (threadIdx.x == 0) {
        unsigned int s = 0;
        for (int b = 0; b < NBKT; ++b) { segStart[b] = s; cursor[b] = s; s += cnt[b]; }
        segStart[NBKT] = s;
    }
}

// ---------------- pass 3: stable-ish counting-sort scatter ----------------
__global__ __launch_bounds__(256) void scatter_kernel(
    const int* __restrict__ eli, int E, float scale,
    unsigned int* __restrict__ cursor,
    uint2* __restrict__ sorted, unsigned int* __restrict__ inv)
{
    __shared__ unsigned int lcnt[NBKT];
    __shared__ unsigned int lpos[NBKT];
    __shared__ int s_i64;
    if (threadIdx.x < NBKT) lcnt[threadIdx.x] = 0;
    if (threadIdx.x == 0) s_i64 = probe_i64(eli);
    __syncthreads();
    const int i64f = s_i64;

    const int chunk = (E + gridDim.x - 1) / gridDim.x;
    const int e0 = blockIdx.x * chunk;
    const int e1 = min(E, e0 + chunk);

    for (int e = e0 + threadIdx.x; e < e1; e += blockDim.x) {
        int c = i64f ? eli[2 * ((size_t)E + e)] : eli[(size_t)E + e];
        int bkt = (int)((float)c * scale);
        if (bkt > NBKT - 1) bkt = NBKT - 1;
        atomicAdd(&lcnt[bkt], 1u);
    }
    __syncthreads();
    if (threadIdx.x < NBKT) {
        unsigned int nv = lcnt[threadIdx.x];
        lpos[threadIdx.x] = nv ? atomicAdd(&cursor[threadIdx.x], nv) : 0u;
    }
    __syncthreads();
    for (int e = e0 + threadIdx.x; e < e1; e += blockDim.x) {
        int r, c;
        if (i64f) { r = eli[2 * (size_t)e]; c = eli[2 * ((size_t)E + e)]; }
        else      { r = eli[e];             c = eli[(size_t)E + e]; }
        int bkt = (int)((float)c * scale);
        if (bkt > NBKT - 1) bkt = NBKT - 1;
        unsigned int pos = atomicAdd(&lpos[bkt], 1u);
        sorted[pos] = make_uint2((unsigned)r, (unsigned)c);
        inv[e] = pos;
    }
}

// ---------------- main: bucketed fused edge-MLP (fp16, XCD-affine) ----------------
// Bucket b processed only by blocks with blockIdx%8 == b%8 (blockIdx round-robins
// XCDs) -> each XCD's live dst slice (~0.8 MB) stays L2-resident. Per wave:
// 16-edge tile, private 4 KB Z, dist-1 register prefetch, 16x16x32_f16 MFMA.
__global__ __launch_bounds__(BLOCK, 3) void mlp_sorted_kernel(
    const _Float16* __restrict__ srcb, const _Float16* __restrict__ dstb,
    const uint2* __restrict__ sorted, const unsigned int* __restrict__ segStart,
    const float* __restrict__ W1, const float* __restrict__ b1,
    const float* __restrict__ W2, const float* __restrict__ b2,
    float* __restrict__ tmp, int E)
{
    __shared__ __align__(16) char lds[49152];   // [0,32K)=W1^T fp16, [32K,48K)=4x4K Z

    const int tid  = threadIdx.x;
    const int lane = tid & 63;
    const int w    = tid >> 6;
    const int rr   = lane & 15;
    const int kgrp = lane >> 4;
    const int rq8  = lane >> 3;
    const int cl   = lane & 7;

    for (int idx = tid; idx < 128 * 128; idx += BLOCK) {
        int k = idx >> 7, n = idx & 127;
        *(_Float16*)(lds + swz16(n, k * 2)) = (_Float16)W1[idx];
    }
    __syncthreads();   // the ONLY barrier

    char* zb = lds + 32768 + (w << 12);

    float b1s[8], w2s[8];
    #pragma unroll
    for (int cb = 0; cb < 8; ++cb) {
        b1s[cb] = b1[cb * 16 + rr];
        w2s[cb] = W2[cb * 16 + rr];
    }
    const float bias2 = b2[0];

    const int x     = blockIdx.x & 7;        // XCD slot
    const int kb    = blockIdx.x >> 3;       // block index within slot
    const int nbs   = gridDim.x >> 3;        // blocks per slot
    const int wslot = kb * 4 + w;            // wave id within slot
    const int wstep = nbs * 4;               // waves per slot

    half8 sv[4], dv[4];
    const half8* s8 = (const half8*)srcb;    // 16 chunks per 256-B row
    const half8* d8 = (const half8*)dstb;

    for (int j = 0; j < NBKT / 8; ++j) {
        const int b  = x + 8 * j;
        const int s0 = (int)segStart[b];
        const int s1 = (int)segStart[b + 1];
        if (s1 <= s0) continue;
        const int nt = (s1 - s0 + 15) >> 4;
        int t = wslot;
        if (t >= nt) continue;

        // prologue: load tile t rows
        {
            int idx = s0 + t * 16 + rr; if (idx >= s1) idx = s1 - 1;
            uint2 iv = sorted[idx];
            #pragma unroll
            for (int i = 0; i < 4; ++i) {
                int hr = i * 8 + rq8, e = hr >> 1, hh = hr & 1;
                int r = __shfl((int)iv.x, e, 64);
                int c = __shfl((int)iv.y, e, 64);
                sv[i] = s8[(size_t)r * 16 + hh * 8 + cl];
                dv[i] = d8[(size_t)c * 16 + hh * 8 + cl];
            }
        }

        while (true) {
            const int base = s0 + t * 16;
            int cnt = s1 - base; if (cnt > 16) cnt = 16;

            asm volatile("" ::: "memory");   // order Z writes after prior tile's reads
            #pragma unroll
            for (int i = 0; i < 4; ++i) {    // product (v_pk_mul_f16) -> swizzled Z
                int hr = i * 8 + rq8;
                half8 pr = sv[i] * dv[i];
                *(half8*)(zb + swzH(hr, cl * 16)) = pr;
            }

            const int tn = t + wstep;        // dist-1 prefetch (hides under MFMA)
            if (tn < nt) {
                int idx = s0 + tn * 16 + rr; if (idx >= s1) idx = s1 - 1;
                uint2 iv = sorted[idx];
                #pragma unroll
                for (int i = 0; i < 4; ++i) {
                    int hr = i * 8 + rq8, e = hr >> 1, hh = hr & 1;
                    int r = __shfl((int)iv.x, e, 64);
                    int c = __shfl((int)iv.y, e, 64);
                    sv[i] = s8[(size_t)r * 16 + hh * 8 + cl];
                    dv[i] = d8[(size_t)c * 16 + hh * 8 + cl];
                }
            }
            asm volatile("" ::: "memory");

            f32x4 acc[8];
            #pragma unroll
            for (int cb = 0; cb < 8; ++cb) acc[cb] = (f32x4){0.f, 0.f, 0.f, 0.f};
            __builtin_amdgcn_s_setprio(1);
            #pragma unroll
            for (int kk = 0; kk < 4; ++kk) {
                half8 af = *(const half8*)(zb + swzH(rr * 2 + (kk >> 1),
                                                     (kk & 1) * 64 + kgrp * 16));
                #pragma unroll
                for (int cb = 0; cb < 8; ++cb) {
                    half8 bf = *(const half8*)(lds + swz16(cb * 16 + rr,
                                                           kk * 64 + kgrp * 16));
                    acc[cb] = __builtin_amdgcn_mfma_f32_16x16x32_f16(af, bf, acc[cb], 0, 0, 0);
                }
            }
            __builtin_amdgcn_s_setprio(0);

            #pragma unroll
            for (int r = 0; r < 4; ++r) {
                float p = 0.f;
                #pragma unroll
                for (int cb = 0; cb < 8; ++cb) {
                    float hv = acc[cb][r] + b1s[cb];
                    hv = fmaxf(hv, 0.f);
                    p = fmaf(hv, w2s[cb], p);
                }
                p += __shfl_xor(p, 1, 64);
                p += __shfl_xor(p, 2, 64);
                p += __shfl_xor(p, 4, 64);
                p += __shfl_xor(p, 8, 64);
                int eo = kgrp * 4 + r;
                if (rr == 0 && eo < cnt)
                    __builtin_nontemporal_store(p + bias2, &tmp[base + eo]);
            }
            if (tn >= nt) break;
            t = tn;
        }
    }
}

// ---------------- final: gather-permute (random READS absorb in cache) ----------------
__global__ __launch_bounds__(256) void permute_kernel(
    const float* __restrict__ tmp, const unsigned int* __restrict__ inv,
    float* __restrict__ out, int E)
{
    for (int e = blockIdx.x * blockDim.x + threadIdx.x; e < E;
         e += gridDim.x * blockDim.x)
        out[e] = tmp[inv[e]];
}

// ---------------- fallback: unsorted (r8 structure, fp16) ----------------
// MODE 1: fp16 tables in ws. MODE 0: direct f32 inputs (no ws).
template<int MODE>
__global__ __launch_bounds__(BLOCK, 3) void edge_mlp_fb(
    const float* __restrict__ srcf, const float* __restrict__ dstf,
    const _Float16* __restrict__ srcb, const _Float16* __restrict__ dstb,
    const int* __restrict__ eli,
    const float* __restrict__ W1, const float* __restrict__ b1,
    const float* __restrict__ W2, const float* __restrict__ b2,
    float* __restrict__ out, int E)
{
    __shared__ __align__(16) char lds[49152];
    const int tid  = threadIdx.x;
    const int lane = tid & 63;
    const int w    = tid >> 6;
    const int rr   = lane & 15;
    const int kgrp = lane >> 4;
    const int rq8  = lane >> 3;
    const int cl   = lane & 7;

    for (int idx = tid; idx < 128 * 128; idx += BLOCK) {
        int k = idx >> 7, n = idx & 127;
        *(_Float16*)(lds + swz16(n, k * 2)) = (_Float16)W1[idx];
    }
    int probe = eli[2 * (lane & 31) + 1];
    unsigned long long bl = __ballot(lane < 32 && probe != 0);
    const int i64f = (bl == 0ull) ? 1 : 0;
    __syncthreads();

    char* zb = lds + 32768 + (w << 12);
    float b1s[8], w2s[8];
    #pragma unroll
    for (int cb = 0; cb < 8; ++cb) {
        b1s[cb] = b1[cb * 16 + rr];
        w2s[cb] = W2[cb * 16 + rr];
    }
    const float bias2 = b2[0];

    const int ngroups = (E + GTILE - 1) / GTILE;
    const int step = gridDim.x * 4;
    int g = blockIdx.x * 4 + w;
    if (g >= ngroups) return;

    auto idxload = [&](int gg) -> int {
        gg = gg < ngroups ? gg : ngroups - 1;
        int e = gg * GTILE + rr; if (e >= E) e = E - 1;
        size_t off = (lane < 32) ? (size_t)e : (size_t)E + (size_t)e;
        return i64f ? eli[2 * off] : eli[off];
    };

    half8 sv[4], dv[4];
    auto loadT = [&](int iv) {
        const half8* s8 = (const half8*)srcb;
        const half8* d8 = (const half8*)dstb;
        #pragma unroll
        for (int i = 0; i < 4; ++i) {
            int hr = i * 8 + rq8, e = hr >> 1, hh = hr & 1;
            int r = __shfl(iv, e, 64);
            int c = __shfl(iv, 32 + e, 64);
            sv[i] = s8[(size_t)r * 16 + hh * 8 + cl];
            dv[i] = d8[(size_t)c * 16 + hh * 8 + cl];
        }
    };
    auto stageF = [&](int iv) {
        const float4* s4 = (const float4*)srcf;
        const float4* d4 = (const float4*)dstf;
        #pragma unroll
        for (int i = 0; i < 4; ++i) {
            int hr = i * 8 + rq8, e = hr >> 1, hh = hr & 1;
            int r = __shfl(iv, e, 64);
            int c = __shfl(iv, 32 + e, 64);
            float4 a0 = s4[(size_t)r * 32 + hh * 16 + cl * 2];
            float4 a1 = s4[(size_t)r * 32 + hh * 16 + cl * 2 + 1];
            float4 c0 = d4[(size_t)c * 32 + hh * 16 + cl * 2];
            float4 c1 = d4[(size_t)c * 32 + hh * 16 + cl * 2 + 1];
            union { _Float16 hf[8]; half8 v; } pr;
            pr.hf[0]=(_Float16)(a0.x*c0.x); pr.hf[1]=(_Float16)(a0.y*c0.y);
            pr.hf[2]=(_Float16)(a0.z*c0.z); pr.hf[3]=(_Float16)(a0.w*c0.w);
            pr.hf[4]=(_Float16)(a1.x*c1.x); pr.hf[5]=(_Float16)(a1.y*c1.y);
            pr.hf[6]=(_Float16)(a1.z*c1.z); pr.hf[7]=(_Float16)(a1.w*c1.w);
            *(half8*)(zb + swzH(hr, cl * 16)) = pr.v;
        }
    };
    auto compute = [&](int gg) {
        f32x4 acc[8];
        #pragma unroll
        for (int cb = 0; cb < 8; ++cb) acc[cb] = (f32x4){0.f, 0.f, 0.f, 0.f};
        __builtin_amdgcn_s_setprio(1);
        #pragma unroll
        for (int kk = 0; kk < 4; ++kk) {
            half8 af = *(const half8*)(zb + swzH(rr * 2 + (kk >> 1),
                                                 (kk & 1) * 64 + kgrp * 16));
            #pragma unroll
            for (int cb = 0; cb < 8; ++cb) {
                half8 bf = *(const half8*)(lds + swz16(cb * 16 + rr,
                                                       kk * 64 + kgrp * 16));
                acc[cb] = __builtin_amdgcn_mfma_f32_16x16x32_f16(af, bf, acc[cb], 0, 0, 0);
            }
        }
        __builtin_amdgcn_s_setprio(0);
        #pragma unroll
        for (int r = 0; r < 4; ++r) {
            float p = 0.f;
            #pragma unroll
            for (int cb = 0; cb < 8; ++cb) {
                float hv = acc[cb][r] + b1s[cb];
                hv = fmaxf(hv, 0.f);
                p = fmaf(hv, w2s[cb], p);
            }
            p += __shfl_xor(p, 1, 64);
            p += __shfl_xor(p, 2, 64);
            p += __shfl_xor(p, 4, 64);
            p += __shfl_xor(p, 8, 64);
            int e = gg * GTILE + kgrp * 4 + r;
            if (rr == 0 && e < E)
                __builtin_nontemporal_store(p + bias2, &out[e]);
        }
    };

    if constexpr (MODE == 1) {
        int iv = idxload(g);
        loadT(iv);
        while (true) {
            asm volatile("" ::: "memory");
            #pragma unroll
            for (int i = 0; i < 4; ++i) {
                int hr = i * 8 + rq8;
                half8 pr = sv[i] * dv[i];
                *(half8*)(zb + swzH(hr, cl * 16)) = pr;
            }
            int gn = g + step;
            if (gn < ngroups) { int iv2 = idxload(gn); loadT(iv2); }
            asm volatile("" ::: "memory");
            compute(g);
            if (gn >= ngroups) break;
            g = gn;
        }
    } else {
        for (; g < ngroups; g += step) {
            asm volatile("" ::: "memory");
            int iv = idxload(g);
            stageF(iv);
            asm volatile("" ::: "memory");
            compute(g);
        }
    }
}

extern "C" void kernel_launch(void* const* d_in, const int* in_sizes, int n_in,
                              void* d_out, int out_size, void* d_ws, size_t ws_size,
                              hipStream_t stream) {
    const float* src = (const float*)d_in[0];
    const float* dst = (const float*)d_in[1];
    const int*   eli = (const int*)d_in[2];
    const float* W1  = (const float*)d_in[3];
    const float* b1  = (const float*)d_in[4];
    const float* W2  = (const float*)d_in[5];
    const float* b2  = (const float*)d_in[6];
    float* out = (float*)d_out;

    const int E = in_sizes[2] / 2;
    const int n = in_sizes[0];               // N * 128 floats
    const int N = n / 128;
    const float scale = (float)NBKT / (float)N;

    const size_t NB = (size_t)n * sizeof(_Float16);   // one fp16 table
    const size_t need_full = 4096 + 2 * NB + (size_t)E * 16;
    const size_t need_tab  = 2 * NB;

    if (ws_size >= need_full) {
        char* wsb = (char*)d_ws;
        unsigned int* cnt      = (unsigned int*)wsb;          // [32]
        unsigned int* segStart = cnt + 32;                    // [33]
        unsigned int* cursor   = segStart + 40;               // [32]
        _Float16* srcb = (_Float16*)(wsb + 4096);
        _Float16* dstb = srcb + n;
        uint2* sorted  = (uint2*)(wsb + 4096 + 2 * NB);
        unsigned int* inv = (unsigned int*)(sorted + E);
        float* tmp = (float*)(inv + E);

        hipMemsetAsync(wsb, 0, 4096, stream);
        cvt_hist_kernel<<<dim3(2048), dim3(256), 0, stream>>>(
            src, dst, srcb, dstb, n, eli, E, scale, cnt);
        scan_kernel<<<dim3(1), dim3(64), 0, stream>>>(cnt, segStart, cursor);
        scatter_kernel<<<dim3(256), dim3(256), 0, stream>>>(
            eli, E, scale, cursor, sorted, inv);
        mlp_sorted_kernel<<<dim3(768), dim3(BLOCK), 0, stream>>>(
            srcb, dstb, sorted, segStart, W1, b1, W2, b2, tmp, E);
        permute_kernel<<<dim3(2048), dim3(256), 0, stream>>>(tmp, inv, out, E);
    } else if (ws_size >= need_tab) {
        _Float16* srcb = (_Float16*)d_ws;
        _Float16* dstb = srcb + n;
        // reuse cvt_hist without hist side effects? simplest: run it with cnt
        // pointing at a dummy region inside ws? Not available -> small cvt via
        // fallback: use cvt_hist with cnt = (unsigned int*)dstb is unsafe.
        // Use MODE0 direct-f32 only if we cannot fit the 4 KB header:
        // (need_tab + 4096 check)
        if (ws_size >= need_tab + 4096) {
            char* wsb = (char*)d_ws;
            unsigned int* cnt = (unsigned int*)(wsb + 2 * NB);  // 4 KB tail header
            _Float16* sb = (_Float16*)wsb;
            _Float16* db = sb + n;
            hipMemsetAsync(cnt, 0, 4096, stream);
            cvt_hist_kernel<<<dim3(2048), dim3(256), 0, stream>>>(
                src, dst, sb, db, n, eli, E, scale, cnt);   // hist result unused
            const int ngroups = (E + GTILE - 1) / GTILE;
            int nblocks = (ngroups + 3) / 4;
            int grid = nblocks < 768 ? nblocks : 768;
            edge_mlp_fb<1><<<dim3(grid), dim3(BLOCK), 0, stream>>>(
                src, dst, sb, db, eli, W1, b1, W2, b2, out, E);
        } else {
            const int ngroups = (E + GTILE - 1) / GTILE;
            int nblocks = (ngroups + 3) / 4;
            int grid = nblocks < 768 ? nblocks : 768;
            edge_mlp_fb<0><<<dim3(grid), dim3(BLOCK), 0, stream>>>(
                src, dst, (const _Float16*)nullptr, (const _Float16*)nullptr,
                eli, W1, b1, W2, b2, out, E);
        }
    } else {
        const int ngroups = (E + GTILE - 1) / GTILE;
        int nblocks = (ngroups + 3) / 4;
        int grid = nblocks < 768 ? nblocks : 768;
        edge_mlp_fb<0><<<dim3(grid), dim3(BLOCK), 0, stream>>>(
            src, dst, (const _Float16*)nullptr, (const _Float16*)nullptr,
            eli, W1, b1, W2, b2, out, E);
    }
}